// Round 18
// baseline (365.509 us; speedup 1.0000x reference)
//
#include <hip/hip_runtime.h>
#include <math.h>

#define N_NODES 50000
#define IN_DIM  1000
#define HIDDEN  256
#define N_EDGES 1600000
#define NBLK    196      // ceil(50000/256)
#define NSTEP   63       // ceil(1000/16)
#define GEMM_BLOCKS ((N_NODES + 63) / 64)   // 782
#define SCAT_BLOCKS 512
#define NODES_PER_PART 6250                 // 50000/8

typedef short bf16x8 __attribute__((ext_vector_type(8)));
typedef float f32x16 __attribute__((ext_vector_type(16)));

__device__ __forceinline__ unsigned short f2bf_rne(float f) {
    unsigned u = __builtin_bit_cast(unsigned, f);
    unsigned r = (u + 0x7FFFu + ((u >> 16) & 1u)) >> 16;
    return (unsigned short)r;
}
__device__ __forceinline__ float bf2f(unsigned short b) {
    unsigned u = ((unsigned)b) << 16;
    return __builtin_bit_cast(float, u);
}
__device__ __forceinline__ unsigned cvt_pk_bf16(float a, float b) {
    unsigned r;
    asm("v_cvt_pk_bf16_f32 %0, %1, %2" : "=v"(r) : "v"(a), "v"(b));
    return r;   // [15:0]=bf16(a), [31:16]=bf16(b)
}
#define GLOAD_LDS16(gp, lp) \
    __builtin_amdgcn_global_load_lds((const __attribute__((address_space(1))) unsigned*)(gp), \
                                     (__attribute__((address_space(3))) unsigned*)(lp), 16, 0, 0)

// ---------------- fused W1-pack + degree histogram ----------------
// blocks [0,1024): wsplit (256K elements); [1024,3072): hist grid-stride.
__global__ __launch_bounds__(256) void prep_kernel(const float* __restrict__ W1,
                                                   unsigned short* __restrict__ Wp,
                                                   const int* __restrict__ ei,
                                                   int* __restrict__ cnt) {
    const int tid = threadIdx.x;
    if (blockIdx.x < 1024) {
        int idx = blockIdx.x * 256 + tid;   // 256 cols * 1024 k
        int c = idx >> 10, k = idx & 1023;
        float v = (k < IN_DIM) ? W1[(size_t)k * HIDDEN + c] : 0.0f;
        int ci = c >> 5;
        int step = k >> 4, kk = k & 15;
        int lane = (kk >> 3) * 32 + (c & 31);
        int j = kk & 7;
        Wp[((size_t)(step * 8 + ci) * 64 + lane) * 8 + j] = f2bf_rne(v);
        return;
    }
    int e = (blockIdx.x - 1024) * 256 + tid;
    const int stride = 2048 * 256;
    for (; e < N_EDGES; e += stride) {
        int d = ei[N_EDGES + e];
        if ((unsigned)d < N_NODES) atomicAdd(&cnt[d], 1);
    }
}

// ---------------- 3-phase scan ----------------
__global__ __launch_bounds__(256) void scan_sums(const int* __restrict__ cnt, int* __restrict__ bsum) {
    __shared__ int s[256];
    int t = threadIdx.x;
    int i = blockIdx.x * 256 + t;
    s[t] = (i < N_NODES) ? cnt[i] : 0;
    __syncthreads();
    #pragma unroll
    for (int off = 128; off > 0; off >>= 1) {
        if (t < off) s[t] += s[t + off];
        __syncthreads();
    }
    if (t == 0) bsum[blockIdx.x] = s[0];
}

__global__ __launch_bounds__(256) void scan_top(int* __restrict__ bsum) {
    __shared__ int s[256];
    int t = threadIdx.x;
    int v = (t < NBLK) ? bsum[t] : 0;
    s[t] = v;
    __syncthreads();
    for (int off = 1; off < 256; off <<= 1) {
        int x = (t >= off) ? s[t - off] : 0;
        __syncthreads();
        s[t] += x;
        __syncthreads();
    }
    if (t < NBLK) bsum[t] = s[t] - v;   // exclusive
}

__global__ __launch_bounds__(256) void scan_write(const int* __restrict__ cnt, const int* __restrict__ bsum,
                                                  int* __restrict__ rowoff, int* __restrict__ cursor,
                                                  float* __restrict__ dinv) {
    __shared__ int s[256];
    int t = threadIdx.x;
    int i = blockIdx.x * 256 + t;
    int v = (i < N_NODES) ? cnt[i] : 0;
    s[t] = v;
    __syncthreads();
    for (int off = 1; off < 256; off <<= 1) {
        int x = (t >= off) ? s[t - off] : 0;
        __syncthreads();
        s[t] += x;
        __syncthreads();
    }
    if (i < N_NODES) {
        int ro = bsum[blockIdx.x] + s[t] - v;   // exclusive
        rowoff[i] = ro;
        cursor[i] = ro;
        dinv[i]  = rsqrtf((float)v + 1.0f);
    }
}

// ---------------- FUSED: gemm1 + dst-partitioned scatter ----------------
// Scatter block with (blockIdx&7)==p handles only dst in [p*6250,(p+1)*6250):
// csr/cursor regions become XCD-private -> write-combining in local L2,
// L2-local atomics. Edge dst array re-scanned 8x (L3-served).
__global__ __launch_bounds__(256, 4) void gemm_scatter_fused(const float* __restrict__ X,
                                                             const unsigned short* __restrict__ Wp,
                                                             const float* __restrict__ dinv,
                                                             unsigned short* __restrict__ G1b,
                                                             const int* __restrict__ ei,
                                                             int* __restrict__ cursor,
                                                             int* __restrict__ csr) {
    __shared__ unsigned short sA[2][1024];   // [mt 2][lane 64][8] bf16 = 2KB/buf
    __shared__ unsigned short sB[2][4096];   // [ci 8][lane 64][8]  bf16 = 8KB/buf
    const int tid = threadIdx.x;

    if (blockIdx.x >= GEMM_BLOCKS) {
        // ---- partitioned scatter path ----
        const int sb   = blockIdx.x - GEMM_BLOCKS;   // 0..511
        const int part = blockIdx.x & 7;             // = this block's XCD (round-robin)
        const int q    = sb >> 3;                    // 0..63 within partition
        const int lo   = part * NODES_PER_PART;
        const int hi   = lo + NODES_PER_PART;
        int e = q * 256 + tid;
        const int stride = (SCAT_BLOCKS / 8) * 256;  // 16384
        for (; e < N_EDGES; e += stride) {
            int d = ei[N_EDGES + e];
            if (d >= lo && d < hi) {
                int s = ei[e];
                if ((unsigned)s < N_NODES) {
                    int pos = atomicAdd(&cursor[d], 1);
                    csr[pos] = s;
                }
            }
        }
        return;
    }

    // ---- gemm1 path (round-16/17 known-good) ----
    const int w   = tid >> 6;
    const int l   = tid & 63;
    const int lr  = l & 31;
    const int lq  = l >> 5;
    const int R   = w >> 1;
    const int C   = w & 1;
    const int m0  = blockIdx.x * 64;

    const int rl = tid >> 2;
    const int ss = tid & 3;
    const int smt   = rl >> 5;
    const int slane = (ss >> 1) * 32 + (rl & 31);
    const int sidx  = smt * 512 + slane * 8 + (ss & 1) * 4;   // shorts
    int rg = m0 + rl;
    const float* ap = X + (size_t)(rg < N_NODES ? rg : N_NODES - 1) * IN_DIM + ss * 4;
    const bool svalid_tail = (ss < 2);

    const unsigned short* bsrc = Wp + (size_t)(w * 2) * 512 + l * 8;

    f32x16 acc[4] = {};

    auto stageB = [&](int s, int buf) {
        const unsigned short* src = bsrc + (size_t)s * 4096;
        GLOAD_LDS16(src,       &sB[buf][(w * 2 + 0) * 512]);
        GLOAD_LDS16(src + 512, &sB[buf][(w * 2 + 1) * 512]);
    };
    auto cvtWriteA = [&](float4 f, int buf) {
        unsigned h0 = cvt_pk_bf16(f.x, f.y);
        unsigned h1 = cvt_pk_bf16(f.z, f.w);
        *(uint2*)&sA[buf][sidx] = make_uint2(h0, h1);
    };

    stageB(0, 0);
    cvtWriteA(*(const float4*)ap, 0);
    float4 rA = *(const float4*)(ap + 16);
    __syncthreads();

    #pragma unroll 1
    for (int s = 0; s < NSTEP; ++s) {
        const int buf = s & 1;
        if (s + 1 < NSTEP) stageB(s + 1, buf ^ 1);
        float4 rN = make_float4(0.f, 0.f, 0.f, 0.f);
        if (s + 2 < NSTEP && (s + 2 < NSTEP - 1 || svalid_tail))
            rN = *(const float4*)(ap + (size_t)(s + 2) * 16);
        if (s + 1 < NSTEP) cvtWriteA(rA, buf ^ 1);

        bf16x8 ah = *(const bf16x8*)&sA[buf][R * 512 + l * 8];
        bf16x8 b[4];
        #pragma unroll
        for (int ni = 0; ni < 4; ++ni)
            b[ni] = *(const bf16x8*)&sB[buf][(C * 4 + ni) * 512 + l * 8];
        #pragma unroll
        for (int ni = 0; ni < 4; ++ni)
            acc[ni] = __builtin_amdgcn_mfma_f32_32x32x16_bf16(ah, b[ni], acc[ni], 0, 0, 0);
        rA = rN;
        __syncthreads();
    }

    // epilogue -> slab-major: G1b[(slab*N + row)*32 + lr], slab = C*4+ni
    #pragma unroll
    for (int r = 0; r < 16; ++r) {
        int row = m0 + R * 32 + (r & 3) + 8 * (r >> 2) + 4 * lq;
        if (row >= N_NODES) continue;
        float dv = dinv[row];
        #pragma unroll
        for (int ni = 0; ni < 4; ++ni) {
            int slab = C * 4 + ni;
            G1b[((size_t)slab * N_NODES + row) * 32 + lr] = f2bf_rne(dv * acc[ni][r]);
        }
    }
}

// ---------------- slab-partitioned agg1 + partial gemm2 -> atomic g2raw ----------------
__global__ __launch_bounds__(256) void aggslab_kernel(const unsigned short* __restrict__ G,
                                                      const int* __restrict__ csr,
                                                      const int* __restrict__ rowoff,
                                                      const int* __restrict__ cnt,
                                                      const float* __restrict__ dinv,
                                                      const float* __restrict__ b1,
                                                      const float* __restrict__ W2,
                                                      float* __restrict__ g2raw) {
    const int tid  = threadIdx.x;
    const int slab = blockIdx.x & 7;
    const int nb   = blockIdx.x >> 3;
    const int wave = tid >> 6, lane = tid & 63;
    const int g    = lane >> 3, sl = lane & 7;
    const int d    = nb * 32 + wave * 8 + g;
    if (d >= N_NODES) return;
    const unsigned short* Gs = G + (size_t)slab * N_NODES * 32;
    const int co = sl * 4;
    const int c0 = slab * 32 + co;

    ushort4 sv = *(const ushort4*)&Gs[(size_t)d * 32 + co];
    float ax = bf2f(sv.x), ay = bf2f(sv.y), az = bf2f(sv.z), aw = bf2f(sv.w);
    int beg = rowoff[d], num = cnt[d];
    int end = beg + num;
    int e = beg;
    for (; e + 8 <= end; e += 8) {
        int s0 = csr[e], s1 = csr[e+1], s2 = csr[e+2], s3 = csr[e+3];
        int s4 = csr[e+4], s5 = csr[e+5], s6 = csr[e+6], s7 = csr[e+7];
        ushort4 v0 = *(const ushort4*)&Gs[(size_t)s0 * 32 + co];
        ushort4 v1 = *(const ushort4*)&Gs[(size_t)s1 * 32 + co];
        ushort4 v2 = *(const ushort4*)&Gs[(size_t)s2 * 32 + co];
        ushort4 v3 = *(const ushort4*)&Gs[(size_t)s3 * 32 + co];
        ushort4 v4 = *(const ushort4*)&Gs[(size_t)s4 * 32 + co];
        ushort4 v5 = *(const ushort4*)&Gs[(size_t)s5 * 32 + co];
        ushort4 v6 = *(const ushort4*)&Gs[(size_t)s6 * 32 + co];
        ushort4 v7 = *(const ushort4*)&Gs[(size_t)s7 * 32 + co];
        ax += bf2f(v0.x); ay += bf2f(v0.y); az += bf2f(v0.z); aw += bf2f(v0.w);
        ax += bf2f(v1.x); ay += bf2f(v1.y); az += bf2f(v1.z); aw += bf2f(v1.w);
        ax += bf2f(v2.x); ay += bf2f(v2.y); az += bf2f(v2.z); aw += bf2f(v2.w);
        ax += bf2f(v3.x); ay += bf2f(v3.y); az += bf2f(v3.z); aw += bf2f(v3.w);
        ax += bf2f(v4.x); ay += bf2f(v4.y); az += bf2f(v4.z); aw += bf2f(v4.w);
        ax += bf2f(v5.x); ay += bf2f(v5.y); az += bf2f(v5.z); aw += bf2f(v5.w);
        ax += bf2f(v6.x); ay += bf2f(v6.y); az += bf2f(v6.z); aw += bf2f(v6.w);
        ax += bf2f(v7.x); ay += bf2f(v7.y); az += bf2f(v7.z); aw += bf2f(v7.w);
    }
    for (; e < end; ++e) {
        int s = csr[e];
        ushort4 v = *(const ushort4*)&Gs[(size_t)s * 32 + co];
        ax += bf2f(v.x); ay += bf2f(v.y); az += bf2f(v.z); aw += bf2f(v.w);
    }
    float dv = dinv[d];
    float4 bb = *(const float4*)&b1[c0];
    float zx = fmaxf(dv * ax + bb.x, 0.f);
    float zy = fmaxf(dv * ay + bb.y, 0.f);
    float zz = fmaxf(dv * az + bb.z, 0.f);
    float zw = fmaxf(dv * aw + bb.w, 0.f);
    float2 w0 = *(const float2*)&W2[(c0 + 0) * 2];
    float2 w1 = *(const float2*)&W2[(c0 + 1) * 2];
    float2 w2_ = *(const float2*)&W2[(c0 + 2) * 2];
    float2 w3 = *(const float2*)&W2[(c0 + 3) * 2];
    float p0 = zx * w0.x + zy * w1.x + zz * w2_.x + zw * w3.x;
    float p1 = zx * w0.y + zy * w1.y + zz * w2_.y + zw * w3.y;
    #pragma unroll
    for (int off = 1; off < 8; off <<= 1) {
        p0 += __shfl_xor(p0, off, 64);
        p1 += __shfl_xor(p1, off, 64);
    }
    if (sl == 0) {
        atomicAdd(&g2raw[d * 2 + 0], p0);
        atomicAdd(&g2raw[d * 2 + 1], p1);
    }
}

// ---------------- agg2: out[d] = dinv[d]*(sum_src dinv[s]*g2raw[s] + dinv[d]*g2raw[d]) + b2
__global__ __launch_bounds__(256) void agg2_kernel(const float* __restrict__ g2raw,
                                                   const int* __restrict__ csr,
                                                   const int* __restrict__ rowoff,
                                                   const int* __restrict__ cnt,
                                                   const float* __restrict__ dinv,
                                                   const float* __restrict__ b2,
                                                   float* __restrict__ out) {
    int wave = threadIdx.x >> 6, lane = threadIdx.x & 63;
    int d = blockIdx.x * 4 + wave;
    if (d >= N_NODES) return;
    int beg = rowoff[d], num = cnt[d];
    float a0 = 0.f, a1 = 0.f;
    for (int e = lane; e < num; e += 64) {
        int s = csr[beg + e];
        float2 g = *(const float2*)&g2raw[s * 2];
        float ds = dinv[s];
        a0 += ds * g.x; a1 += ds * g.y;
    }
    #pragma unroll
    for (int off = 32; off; off >>= 1) {
        a0 += __shfl_xor(a0, off, 64);
        a1 += __shfl_xor(a1, off, 64);
    }
    if (lane == 0) {
        float2 self = *(const float2*)&g2raw[d * 2];
        float dv = dinv[d];
        out[d * 2 + 0] = dv * (a0 + dv * self.x) + b2[0];
        out[d * 2 + 1] = dv * (a1 + dv * self.y) + b2[1];
    }
}

// ---------------- workspace layout (bytes) ----------------
#define OFF_CNT     0u
#define OFF_ROWOFF  262144u
#define OFF_CURSOR  524288u
#define OFF_DINV    786432u
#define OFF_BSUM    1048576u
#define OFF_CSR     1310720u
#define OFF_WP      8388608u     // 512 KB packed single-plane
#define OFF_G1B     9437184u     // 25.6 MB slab-major
#define OFF_G2      35651584u    // 400 KB (g2raw, atomic accum)
// total ~36 MB

extern "C" void kernel_launch(void* const* d_in, const int* in_sizes, int n_in,
                              void* d_out, int out_size, void* d_ws, size_t ws_size,
                              hipStream_t stream) {
    const float* x  = (const float*)d_in[0];
    const float* W1 = (const float*)d_in[1];
    const float* b1 = (const float*)d_in[2];
    const float* W2 = (const float*)d_in[3];
    const float* b2 = (const float*)d_in[4];
    const int*   ei = (const int*)d_in[5];

    char* ws = (char*)d_ws;
    int*   cnt    = (int*)  (ws + OFF_CNT);
    int*   rowoff = (int*)  (ws + OFF_ROWOFF);
    int*   cursor = (int*)  (ws + OFF_CURSOR);
    float* dinv   = (float*)(ws + OFF_DINV);
    int*   bsum   = (int*)  (ws + OFF_BSUM);
    int*   csr    = (int*)  (ws + OFF_CSR);
    unsigned short* wp  = (unsigned short*)(ws + OFF_WP);
    unsigned short* g1b = (unsigned short*)(ws + OFF_G1B);
    float* g2raw  = (float*)(ws + OFF_G2);
    float* out    = (float*)d_out;

    hipMemsetAsync(cnt, 0, N_NODES * sizeof(int), stream);
    hipMemsetAsync(g2raw, 0, N_NODES * 2 * sizeof(float), stream);

    prep_kernel<<<3072, 256, 0, stream>>>(W1, wp, ei, cnt);
    scan_sums<<<NBLK, 256, 0, stream>>>(cnt, bsum);
    scan_top<<<1, 256, 0, stream>>>(bsum);
    scan_write<<<NBLK, 256, 0, stream>>>(cnt, bsum, rowoff, cursor, dinv);

    gemm_scatter_fused<<<GEMM_BLOCKS + SCAT_BLOCKS, 256, 0, stream>>>(x, wp, dinv, g1b,
                                                                      ei, cursor, csr);

    aggslab_kernel<<<8 * ((N_NODES + 31) / 32), 256, 0, stream>>>(g1b, csr, rowoff, cnt, dinv, b1, W2, g2raw);
    agg2_kernel<<<(N_NODES + 3) / 4, 256, 0, stream>>>(g2raw, csr, rowoff, cnt, dinv, b2, out);
}

// Round 19
// 323.113 us; speedup vs baseline: 1.1312x; 1.1312x over previous
//
#include <hip/hip_runtime.h>
#include <math.h>

#define N_NODES 50000
#define IN_DIM  1000
#define HIDDEN  256
#define N_EDGES 1600000
#define NBLK    196      // ceil(50000/256)
#define NSTEP   63       // ceil(1000/16)
#define GEMM_BLOCKS ((N_NODES + 63) / 64)   // 782
#define SCAT_BLOCKS 512

typedef short bf16x8 __attribute__((ext_vector_type(8)));
typedef float f32x16 __attribute__((ext_vector_type(16)));

__device__ __forceinline__ unsigned short f2bf_rne(float f) {
    unsigned u = __builtin_bit_cast(unsigned, f);
    unsigned r = (u + 0x7FFFu + ((u >> 16) & 1u)) >> 16;
    return (unsigned short)r;
}
__device__ __forceinline__ float bf2f(unsigned short b) {
    unsigned u = ((unsigned)b) << 16;
    return __builtin_bit_cast(float, u);
}
__device__ __forceinline__ unsigned cvt_pk_bf16(float a, float b) {
    unsigned r;
    asm("v_cvt_pk_bf16_f32 %0, %1, %2" : "=v"(r) : "v"(a), "v"(b));
    return r;   // [15:0]=bf16(a), [31:16]=bf16(b)
}
#define GLOAD_LDS16(gp, lp) \
    __builtin_amdgcn_global_load_lds((const __attribute__((address_space(1))) unsigned*)(gp), \
                                     (__attribute__((address_space(3))) unsigned*)(lp), 16, 0, 0)

// ---------------- fused W1-pack + degree histogram ----------------
// blocks [0,1024): wsplit (256K elements); [1024,3072): hist grid-stride.
__global__ __launch_bounds__(256) void prep_kernel(const float* __restrict__ W1,
                                                   unsigned short* __restrict__ Wp,
                                                   const int* __restrict__ ei,
                                                   int* __restrict__ cnt) {
    const int tid = threadIdx.x;
    if (blockIdx.x < 1024) {
        int idx = blockIdx.x * 256 + tid;   // 256 cols * 1024 k
        int c = idx >> 10, k = idx & 1023;
        float v = (k < IN_DIM) ? W1[(size_t)k * HIDDEN + c] : 0.0f;
        int ci = c >> 5;
        int step = k >> 4, kk = k & 15;
        int lane = (kk >> 3) * 32 + (c & 31);
        int j = kk & 7;
        Wp[((size_t)(step * 8 + ci) * 64 + lane) * 8 + j] = f2bf_rne(v);
        return;
    }
    int e = (blockIdx.x - 1024) * 256 + tid;
    const int stride = 2048 * 256;
    for (; e < N_EDGES; e += stride) {
        int d = ei[N_EDGES + e];
        if ((unsigned)d < N_NODES) atomicAdd(&cnt[d], 1);
    }
}

// ---------------- 3-phase scan ----------------
__global__ __launch_bounds__(256) void scan_sums(const int* __restrict__ cnt, int* __restrict__ bsum) {
    __shared__ int s[256];
    int t = threadIdx.x;
    int i = blockIdx.x * 256 + t;
    s[t] = (i < N_NODES) ? cnt[i] : 0;
    __syncthreads();
    #pragma unroll
    for (int off = 128; off > 0; off >>= 1) {
        if (t < off) s[t] += s[t + off];
        __syncthreads();
    }
    if (t == 0) bsum[blockIdx.x] = s[0];
}

__global__ __launch_bounds__(256) void scan_top(int* __restrict__ bsum) {
    __shared__ int s[256];
    int t = threadIdx.x;
    int v = (t < NBLK) ? bsum[t] : 0;
    s[t] = v;
    __syncthreads();
    for (int off = 1; off < 256; off <<= 1) {
        int x = (t >= off) ? s[t - off] : 0;
        __syncthreads();
        s[t] += x;
        __syncthreads();
    }
    if (t < NBLK) bsum[t] = s[t] - v;   // exclusive
}

__global__ __launch_bounds__(256) void scan_write(const int* __restrict__ cnt, const int* __restrict__ bsum,
                                                  int* __restrict__ rowoff, int* __restrict__ cursor,
                                                  float* __restrict__ dinv) {
    __shared__ int s[256];
    int t = threadIdx.x;
    int i = blockIdx.x * 256 + t;
    int v = (i < N_NODES) ? cnt[i] : 0;
    s[t] = v;
    __syncthreads();
    for (int off = 1; off < 256; off <<= 1) {
        int x = (t >= off) ? s[t - off] : 0;
        __syncthreads();
        s[t] += x;
        __syncthreads();
    }
    if (i < N_NODES) {
        int ro = bsum[blockIdx.x] + s[t] - v;   // exclusive
        rowoff[i] = ro;
        cursor[i] = ro;
        dinv[i]  = rsqrtf((float)v + 1.0f);
    }
}

// ---------------- FUSED: gemm1 (blocks [0,GEMM_BLOCKS)) + scatter (rest) ----------------
__global__ __launch_bounds__(256, 4) void gemm_scatter_fused(const float* __restrict__ X,
                                                             const unsigned short* __restrict__ Wp,
                                                             const float* __restrict__ dinv,
                                                             unsigned short* __restrict__ G1b,
                                                             const int* __restrict__ ei,
                                                             int* __restrict__ cursor,
                                                             int* __restrict__ csr) {
    __shared__ unsigned short sA[2][1024];   // [mt 2][lane 64][8] bf16 = 2KB/buf
    __shared__ unsigned short sB[2][4096];   // [ci 8][lane 64][8]  bf16 = 8KB/buf
    const int tid = threadIdx.x;

    if (blockIdx.x >= GEMM_BLOCKS) {
        // ---- scatter path (grid-stride over edges) ----
        int e = (blockIdx.x - GEMM_BLOCKS) * 256 + tid;
        int stride = SCAT_BLOCKS * 256;
        for (; e < N_EDGES; e += stride) {
            int s = ei[e];
            int d = ei[N_EDGES + e];
            if ((unsigned)d < N_NODES && (unsigned)s < N_NODES) {
                int pos = atomicAdd(&cursor[d], 1);
                csr[pos] = s;
            }
        }
        return;
    }

    // ---- gemm1 path (round-16/17 known-good) ----
    const int w   = tid >> 6;
    const int l   = tid & 63;
    const int lr  = l & 31;
    const int lq  = l >> 5;
    const int R   = w >> 1;
    const int C   = w & 1;
    const int m0  = blockIdx.x * 64;

    const int rl = tid >> 2;
    const int ss = tid & 3;
    const int smt   = rl >> 5;
    const int slane = (ss >> 1) * 32 + (rl & 31);
    const int sidx  = smt * 512 + slane * 8 + (ss & 1) * 4;   // shorts
    int rg = m0 + rl;
    const float* ap = X + (size_t)(rg < N_NODES ? rg : N_NODES - 1) * IN_DIM + ss * 4;
    const bool svalid_tail = (ss < 2);

    const unsigned short* bsrc = Wp + (size_t)(w * 2) * 512 + l * 8;

    f32x16 acc[4] = {};

    auto stageB = [&](int s, int buf) {
        const unsigned short* src = bsrc + (size_t)s * 4096;
        GLOAD_LDS16(src,       &sB[buf][(w * 2 + 0) * 512]);
        GLOAD_LDS16(src + 512, &sB[buf][(w * 2 + 1) * 512]);
    };
    auto cvtWriteA = [&](float4 f, int buf) {
        unsigned h0 = cvt_pk_bf16(f.x, f.y);
        unsigned h1 = cvt_pk_bf16(f.z, f.w);
        *(uint2*)&sA[buf][sidx] = make_uint2(h0, h1);
    };

    stageB(0, 0);
    cvtWriteA(*(const float4*)ap, 0);
    float4 rA = *(const float4*)(ap + 16);
    __syncthreads();

    #pragma unroll 1
    for (int s = 0; s < NSTEP; ++s) {
        const int buf = s & 1;
        if (s + 1 < NSTEP) stageB(s + 1, buf ^ 1);
        float4 rN = make_float4(0.f, 0.f, 0.f, 0.f);
        if (s + 2 < NSTEP && (s + 2 < NSTEP - 1 || svalid_tail))
            rN = *(const float4*)(ap + (size_t)(s + 2) * 16);
        if (s + 1 < NSTEP) cvtWriteA(rA, buf ^ 1);

        bf16x8 ah = *(const bf16x8*)&sA[buf][R * 512 + l * 8];
        bf16x8 b[4];
        #pragma unroll
        for (int ni = 0; ni < 4; ++ni)
            b[ni] = *(const bf16x8*)&sB[buf][(C * 4 + ni) * 512 + l * 8];
        #pragma unroll
        for (int ni = 0; ni < 4; ++ni)
            acc[ni] = __builtin_amdgcn_mfma_f32_32x32x16_bf16(ah, b[ni], acc[ni], 0, 0, 0);
        rA = rN;
        __syncthreads();
    }

    // epilogue -> slab-major: G1b[(slab*N + row)*32 + lr], slab = C*4+ni
    #pragma unroll
    for (int r = 0; r < 16; ++r) {
        int row = m0 + R * 32 + (r & 3) + 8 * (r >> 2) + 4 * lq;
        if (row >= N_NODES) continue;
        float dv = dinv[row];
        #pragma unroll
        for (int ni = 0; ni < 4; ++ni) {
            int slab = C * 4 + ni;
            G1b[((size_t)slab * N_NODES + row) * 32 + lr] = f2bf_rne(dv * acc[ni][r]);
        }
    }
}

// ---------------- slab-partitioned agg1 + partial gemm2 (slab-major g1b) ----------------
__global__ __launch_bounds__(256) void aggslab_kernel(const unsigned short* __restrict__ G,
                                                      const int* __restrict__ csr,
                                                      const int* __restrict__ rowoff,
                                                      const int* __restrict__ cnt,
                                                      const float* __restrict__ dinv,
                                                      const float* __restrict__ b1,
                                                      const float* __restrict__ W2,
                                                      float* __restrict__ part) {
    const int tid  = threadIdx.x;
    const int slab = blockIdx.x & 7;
    const int nb   = blockIdx.x >> 3;
    const int wave = tid >> 6, lane = tid & 63;
    const int g    = lane >> 3, sl = lane & 7;
    const int d    = nb * 32 + wave * 8 + g;
    if (d >= N_NODES) return;
    const unsigned short* Gs = G + (size_t)slab * N_NODES * 32;
    const int co = sl * 4;
    const int c0 = slab * 32 + co;

    ushort4 sv = *(const ushort4*)&Gs[(size_t)d * 32 + co];
    float ax = bf2f(sv.x), ay = bf2f(sv.y), az = bf2f(sv.z), aw = bf2f(sv.w);
    int beg = rowoff[d], num = cnt[d];
    int end = beg + num;
    int e = beg;
    for (; e + 8 <= end; e += 8) {
        int s0 = csr[e], s1 = csr[e+1], s2 = csr[e+2], s3 = csr[e+3];
        int s4 = csr[e+4], s5 = csr[e+5], s6 = csr[e+6], s7 = csr[e+7];
        ushort4 v0 = *(const ushort4*)&Gs[(size_t)s0 * 32 + co];
        ushort4 v1 = *(const ushort4*)&Gs[(size_t)s1 * 32 + co];
        ushort4 v2 = *(const ushort4*)&Gs[(size_t)s2 * 32 + co];
        ushort4 v3 = *(const ushort4*)&Gs[(size_t)s3 * 32 + co];
        ushort4 v4 = *(const ushort4*)&Gs[(size_t)s4 * 32 + co];
        ushort4 v5 = *(const ushort4*)&Gs[(size_t)s5 * 32 + co];
        ushort4 v6 = *(const ushort4*)&Gs[(size_t)s6 * 32 + co];
        ushort4 v7 = *(const ushort4*)&Gs[(size_t)s7 * 32 + co];
        ax += bf2f(v0.x); ay += bf2f(v0.y); az += bf2f(v0.z); aw += bf2f(v0.w);
        ax += bf2f(v1.x); ay += bf2f(v1.y); az += bf2f(v1.z); aw += bf2f(v1.w);
        ax += bf2f(v2.x); ay += bf2f(v2.y); az += bf2f(v2.z); aw += bf2f(v2.w);
        ax += bf2f(v3.x); ay += bf2f(v3.y); az += bf2f(v3.z); aw += bf2f(v3.w);
        ax += bf2f(v4.x); ay += bf2f(v4.y); az += bf2f(v4.z); aw += bf2f(v4.w);
        ax += bf2f(v5.x); ay += bf2f(v5.y); az += bf2f(v5.z); aw += bf2f(v5.w);
        ax += bf2f(v6.x); ay += bf2f(v6.y); az += bf2f(v6.z); aw += bf2f(v6.w);
        ax += bf2f(v7.x); ay += bf2f(v7.y); az += bf2f(v7.z); aw += bf2f(v7.w);
    }
    for (; e < end; ++e) {
        int s = csr[e];
        ushort4 v = *(const ushort4*)&Gs[(size_t)s * 32 + co];
        ax += bf2f(v.x); ay += bf2f(v.y); az += bf2f(v.z); aw += bf2f(v.w);
    }
    float dv = dinv[d];
    float4 bb = *(const float4*)&b1[c0];
    float zx = fmaxf(dv * ax + bb.x, 0.f);
    float zy = fmaxf(dv * ay + bb.y, 0.f);
    float zz = fmaxf(dv * az + bb.z, 0.f);
    float zw = fmaxf(dv * aw + bb.w, 0.f);
    float2 w0 = *(const float2*)&W2[(c0 + 0) * 2];
    float2 w1 = *(const float2*)&W2[(c0 + 1) * 2];
    float2 w2_ = *(const float2*)&W2[(c0 + 2) * 2];
    float2 w3 = *(const float2*)&W2[(c0 + 3) * 2];
    float p0 = zx * w0.x + zy * w1.x + zz * w2_.x + zw * w3.x;
    float p1 = zx * w0.y + zy * w1.y + zz * w2_.y + zw * w3.y;
    #pragma unroll
    for (int off = 1; off < 8; off <<= 1) {
        p0 += __shfl_xor(p0, off, 64);
        p1 += __shfl_xor(p1, off, 64);
    }
    if (sl == 0)
        *(float2*)&part[((size_t)slab * N_NODES + d) * 2] = make_float2(p0, p1);
}

// ---------------- g2 = dinv * sum_slab(part) ----------------
__global__ __launch_bounds__(256) void g2reduce_kernel(const float* __restrict__ part,
                                                       const float* __restrict__ dinv,
                                                       float* __restrict__ G2) {
    int i = blockIdx.x * 256 + threadIdx.x;
    if (i >= N_NODES) return;
    float a0 = 0.f, a1 = 0.f;
    #pragma unroll
    for (int s = 0; s < 8; ++s) {
        float2 p = *(const float2*)&part[((size_t)s * N_NODES + i) * 2];
        a0 += p.x; a1 += p.y;
    }
    float dv = dinv[i];
    G2[i * 2 + 0] = dv * a0;
    G2[i * 2 + 1] = dv * a1;
}

// ---------------- agg2 ----------------
__global__ __launch_bounds__(256) void agg2_kernel(const float* __restrict__ G2,
                                                   const int* __restrict__ csr,
                                                   const int* __restrict__ rowoff,
                                                   const int* __restrict__ cnt,
                                                   const float* __restrict__ dinv,
                                                   const float* __restrict__ b2,
                                                   float* __restrict__ out) {
    int wave = threadIdx.x >> 6, lane = threadIdx.x & 63;
    int d = blockIdx.x * 4 + wave;
    if (d >= N_NODES) return;
    int beg = rowoff[d], num = cnt[d];
    float a0 = 0.f, a1 = 0.f;
    for (int e = lane; e < num; e += 64) {
        int s = csr[beg + e];
        float2 g = *(const float2*)&G2[s * 2];
        a0 += g.x; a1 += g.y;
    }
    #pragma unroll
    for (int off = 32; off; off >>= 1) {
        a0 += __shfl_xor(a0, off, 64);
        a1 += __shfl_xor(a1, off, 64);
    }
    if (lane == 0) {
        float2 self = *(const float2*)&G2[d * 2];
        float dv = dinv[d];
        out[d * 2 + 0] = dv * (a0 + self.x) + b2[0];
        out[d * 2 + 1] = dv * (a1 + self.y) + b2[1];
    }
}

// ---------------- workspace layout (bytes) ----------------
#define OFF_CNT     0u
#define OFF_ROWOFF  262144u
#define OFF_CURSOR  524288u
#define OFF_DINV    786432u
#define OFF_BSUM    1048576u
#define OFF_CSR     1310720u
#define OFF_WP      8388608u     // 512 KB packed single-plane
#define OFF_G1B     9437184u     // 25.6 MB slab-major
#define OFF_G2      35651584u    // 400 KB
#define OFF_PART    36700160u    // 3.2 MB
// total ~40 MB

extern "C" void kernel_launch(void* const* d_in, const int* in_sizes, int n_in,
                              void* d_out, int out_size, void* d_ws, size_t ws_size,
                              hipStream_t stream) {
    const float* x  = (const float*)d_in[0];
    const float* W1 = (const float*)d_in[1];
    const float* b1 = (const float*)d_in[2];
    const float* W2 = (const float*)d_in[3];
    const float* b2 = (const float*)d_in[4];
    const int*   ei = (const int*)d_in[5];

    char* ws = (char*)d_ws;
    int*   cnt    = (int*)  (ws + OFF_CNT);
    int*   rowoff = (int*)  (ws + OFF_ROWOFF);
    int*   cursor = (int*)  (ws + OFF_CURSOR);
    float* dinv   = (float*)(ws + OFF_DINV);
    int*   bsum   = (int*)  (ws + OFF_BSUM);
    int*   csr    = (int*)  (ws + OFF_CSR);
    unsigned short* wp  = (unsigned short*)(ws + OFF_WP);
    unsigned short* g1b = (unsigned short*)(ws + OFF_G1B);
    float* g2     = (float*)(ws + OFF_G2);
    float* part   = (float*)(ws + OFF_PART);
    float* out    = (float*)d_out;

    hipMemsetAsync(cnt, 0, N_NODES * sizeof(int), stream);

    prep_kernel<<<3072, 256, 0, stream>>>(W1, wp, ei, cnt);
    scan_sums<<<NBLK, 256, 0, stream>>>(cnt, bsum);
    scan_top<<<1, 256, 0, stream>>>(bsum);
    scan_write<<<NBLK, 256, 0, stream>>>(cnt, bsum, rowoff, cursor, dinv);

    gemm_scatter_fused<<<GEMM_BLOCKS + SCAT_BLOCKS, 256, 0, stream>>>(x, wp, dinv, g1b,
                                                                      ei, cursor, csr);

    aggslab_kernel<<<8 * ((N_NODES + 31) / 32), 256, 0, stream>>>(g1b, csr, rowoff, cnt, dinv, b1, W2, part);
    g2reduce_kernel<<<NBLK, 256, 0, stream>>>(part, dinv, g2);
    agg2_kernel<<<(N_NODES + 3) / 4, 256, 0, stream>>>(g2, csr, rowoff, cnt, dinv, b2, out);
}

// Round 20
// 314.884 us; speedup vs baseline: 1.1608x; 1.0261x over previous
//
#include <hip/hip_runtime.h>
#include <math.h>

#define N_NODES 50000
#define IN_DIM  1000
#define HIDDEN  256
#define N_EDGES 1600000
#define NBLK    196      // ceil(50000/256)
#define NSTEP   63       // ceil(1000/16)
#define GEMM_BLOCKS ((N_NODES + 63) / 64)   // 782
#define SCAT_BLOCKS 512

typedef short bf16x8 __attribute__((ext_vector_type(8)));
typedef float f32x16 __attribute__((ext_vector_type(16)));

__device__ __forceinline__ unsigned short f2bf_rne(float f) {
    unsigned u = __builtin_bit_cast(unsigned, f);
    unsigned r = (u + 0x7FFFu + ((u >> 16) & 1u)) >> 16;
    return (unsigned short)r;
}
__device__ __forceinline__ float bf2f(unsigned short b) {
    unsigned u = ((unsigned)b) << 16;
    return __builtin_bit_cast(float, u);
}
__device__ __forceinline__ unsigned cvt_pk_bf16(float a, float b) {
    unsigned r;
    asm("v_cvt_pk_bf16_f32 %0, %1, %2" : "=v"(r) : "v"(a), "v"(b));
    return r;   // [15:0]=bf16(a), [31:16]=bf16(b)
}
#define GLOAD_LDS16(gp, lp) \
    __builtin_amdgcn_global_load_lds((const __attribute__((address_space(1))) unsigned*)(gp), \
                                     (__attribute__((address_space(3))) unsigned*)(lp), 16, 0, 0)

// ---------------- degree histogram ----------------
__global__ void hist_kernel(const int* __restrict__ ei, int* __restrict__ cnt) {
    int e = blockIdx.x * blockDim.x + threadIdx.x;
    int stride = gridDim.x * blockDim.x;
    for (; e < N_EDGES; e += stride) {
        int d = ei[N_EDGES + e];
        if ((unsigned)d < N_NODES) atomicAdd(&cnt[d], 1);
    }
}

// ---------------- W1 pack, SINGLE bf16 plane ----------------
__global__ __launch_bounds__(256) void wsplit_kernel(const float* __restrict__ W1,
                                                     unsigned short* __restrict__ Wp) {
    int idx = blockIdx.x * 256 + threadIdx.x;   // 256 cols * 1024 k
    int c = idx >> 10, k = idx & 1023;
    float v = (k < IN_DIM) ? W1[(size_t)k * HIDDEN + c] : 0.0f;
    int ci = c >> 5;
    int step = k >> 4, kk = k & 15;
    int lane = (kk >> 3) * 32 + (c & 31);
    int j = kk & 7;
    Wp[((size_t)(step * 8 + ci) * 64 + lane) * 8 + j] = f2bf_rne(v);
}

// ---------------- 3-phase scan ----------------
__global__ __launch_bounds__(256) void scan_sums(const int* __restrict__ cnt, int* __restrict__ bsum) {
    __shared__ int s[256];
    int t = threadIdx.x;
    int i = blockIdx.x * 256 + t;
    s[t] = (i < N_NODES) ? cnt[i] : 0;
    __syncthreads();
    #pragma unroll
    for (int off = 128; off > 0; off >>= 1) {
        if (t < off) s[t] += s[t + off];
        __syncthreads();
    }
    if (t == 0) bsum[blockIdx.x] = s[0];
}

__global__ __launch_bounds__(256) void scan_top(int* __restrict__ bsum) {
    __shared__ int s[256];
    int t = threadIdx.x;
    int v = (t < NBLK) ? bsum[t] : 0;
    s[t] = v;
    __syncthreads();
    for (int off = 1; off < 256; off <<= 1) {
        int x = (t >= off) ? s[t - off] : 0;
        __syncthreads();
        s[t] += x;
        __syncthreads();
    }
    if (t < NBLK) bsum[t] = s[t] - v;   // exclusive
}

__global__ __launch_bounds__(256) void scan_write(const int* __restrict__ cnt, const int* __restrict__ bsum,
                                                  int* __restrict__ rowoff, int* __restrict__ cursor,
                                                  float* __restrict__ dinv) {
    __shared__ int s[256];
    int t = threadIdx.x;
    int i = blockIdx.x * 256 + t;
    int v = (i < N_NODES) ? cnt[i] : 0;
    s[t] = v;
    __syncthreads();
    for (int off = 1; off < 256; off <<= 1) {
        int x = (t >= off) ? s[t - off] : 0;
        __syncthreads();
        s[t] += x;
        __syncthreads();
    }
    if (i < N_NODES) {
        int ro = bsum[blockIdx.x] + s[t] - v;   // exclusive
        rowoff[i] = ro;
        cursor[i] = ro;
        dinv[i]  = rsqrtf((float)v + 1.0f);
    }
}

// ---------------- FUSED: gemm1 (blocks [0,GEMM_BLOCKS)) + scatter (rest) ----------------
__global__ __launch_bounds__(256, 4) void gemm_scatter_fused(const float* __restrict__ X,
                                                             const unsigned short* __restrict__ Wp,
                                                             const float* __restrict__ dinv,
                                                             unsigned short* __restrict__ G1b,
                                                             const int* __restrict__ ei,
                                                             int* __restrict__ cursor,
                                                             int* __restrict__ csr) {
    __shared__ unsigned short sA[2][1024];   // [mt 2][lane 64][8] bf16 = 2KB/buf
    __shared__ unsigned short sB[2][4096];   // [ci 8][lane 64][8]  bf16 = 8KB/buf
    const int tid = threadIdx.x;

    if (blockIdx.x >= GEMM_BLOCKS) {
        // ---- scatter path (grid-stride over edges) ----
        int e = (blockIdx.x - GEMM_BLOCKS) * 256 + tid;
        int stride = SCAT_BLOCKS * 256;
        for (; e < N_EDGES; e += stride) {
            int s = ei[e];
            int d = ei[N_EDGES + e];
            if ((unsigned)d < N_NODES && (unsigned)s < N_NODES) {
                int pos = atomicAdd(&cursor[d], 1);
                csr[pos] = s;
            }
        }
        return;
    }

    // ---- gemm1 path ----
    const int w   = tid >> 6;
    const int l   = tid & 63;
    const int lr  = l & 31;
    const int lq  = l >> 5;
    const int R   = w >> 1;
    const int C   = w & 1;
    const int m0  = blockIdx.x * 64;

    const int rl = tid >> 2;
    const int ss = tid & 3;
    const int smt   = rl >> 5;
    const int slane = (ss >> 1) * 32 + (rl & 31);
    const int sidx  = smt * 512 + slane * 8 + (ss & 1) * 4;   // shorts
    int rg = m0 + rl;
    const float* ap = X + (size_t)(rg < N_NODES ? rg : N_NODES - 1) * IN_DIM + ss * 4;
    const bool svalid_tail = (ss < 2);

    const unsigned short* bsrc = Wp + (size_t)(w * 2) * 512 + l * 8;

    f32x16 acc[4] = {};

    auto stageB = [&](int s, int buf) {
        const unsigned short* src = bsrc + (size_t)s * 4096;
        GLOAD_LDS16(src,       &sB[buf][(w * 2 + 0) * 512]);
        GLOAD_LDS16(src + 512, &sB[buf][(w * 2 + 1) * 512]);
    };
    auto cvtWriteA = [&](float4 f, int buf) {
        unsigned h0 = cvt_pk_bf16(f.x, f.y);
        unsigned h1 = cvt_pk_bf16(f.z, f.w);
        *(uint2*)&sA[buf][sidx] = make_uint2(h0, h1);
    };

    stageB(0, 0);
    cvtWriteA(*(const float4*)ap, 0);
    float4 rA = *(const float4*)(ap + 16);
    __syncthreads();

    #pragma unroll 1
    for (int s = 0; s < NSTEP; ++s) {
        const int buf = s & 1;
        if (s + 1 < NSTEP) stageB(s + 1, buf ^ 1);
        float4 rN = make_float4(0.f, 0.f, 0.f, 0.f);
        if (s + 2 < NSTEP && (s + 2 < NSTEP - 1 || svalid_tail))
            rN = *(const float4*)(ap + (size_t)(s + 2) * 16);
        if (s + 1 < NSTEP) cvtWriteA(rA, buf ^ 1);

        bf16x8 ah = *(const bf16x8*)&sA[buf][R * 512 + l * 8];
        bf16x8 b[4];
        #pragma unroll
        for (int ni = 0; ni < 4; ++ni)
            b[ni] = *(const bf16x8*)&sB[buf][(C * 4 + ni) * 512 + l * 8];
        #pragma unroll
        for (int ni = 0; ni < 4; ++ni)
            acc[ni] = __builtin_amdgcn_mfma_f32_32x32x16_bf16(ah, b[ni], acc[ni], 0, 0, 0);
        rA = rN;
        __syncthreads();
    }

    // epilogue -> slab-major: G1b[(slab*N + row)*32 + lr], slab = C*4+ni
    #pragma unroll
    for (int r = 0; r < 16; ++r) {
        int row = m0 + R * 32 + (r & 3) + 8 * (r >> 2) + 4 * lq;
        if (row >= N_NODES) continue;
        float dv = dinv[row];
        #pragma unroll
        for (int ni = 0; ni < 4; ++ni) {
            int slab = C * 4 + ni;
            G1b[((size_t)slab * N_NODES + row) * 32 + lr] = f2bf_rne(dv * acc[ni][r]);
        }
    }
}

// ---------------- slab-partitioned agg1 + partial gemm2 (slab-major g1b) ----------------
__global__ __launch_bounds__(256) void aggslab_kernel(const unsigned short* __restrict__ G,
                                                      const int* __restrict__ csr,
                                                      const int* __restrict__ rowoff,
                                                      const int* __restrict__ cnt,
                                                      const float* __restrict__ dinv,
                                                      const float* __restrict__ b1,
                                                      const float* __restrict__ W2,
                                                      float* __restrict__ part) {
    const int tid  = threadIdx.x;
    const int slab = blockIdx.x & 7;
    const int nb   = blockIdx.x >> 3;
    const int wave = tid >> 6, lane = tid & 63;
    const int g    = lane >> 3, sl = lane & 7;
    const int d    = nb * 32 + wave * 8 + g;
    if (d >= N_NODES) return;
    const unsigned short* Gs = G + (size_t)slab * N_NODES * 32;
    const int co = sl * 4;
    const int c0 = slab * 32 + co;

    ushort4 sv = *(const ushort4*)&Gs[(size_t)d * 32 + co];
    float ax = bf2f(sv.x), ay = bf2f(sv.y), az = bf2f(sv.z), aw = bf2f(sv.w);
    int beg = rowoff[d], num = cnt[d];
    int end = beg + num;
    int e = beg;
    for (; e + 8 <= end; e += 8) {
        int s0 = csr[e], s1 = csr[e+1], s2 = csr[e+2], s3 = csr[e+3];
        int s4 = csr[e+4], s5 = csr[e+5], s6 = csr[e+6], s7 = csr[e+7];
        ushort4 v0 = *(const ushort4*)&Gs[(size_t)s0 * 32 + co];
        ushort4 v1 = *(const ushort4*)&Gs[(size_t)s1 * 32 + co];
        ushort4 v2 = *(const ushort4*)&Gs[(size_t)s2 * 32 + co];
        ushort4 v3 = *(const ushort4*)&Gs[(size_t)s3 * 32 + co];
        ushort4 v4 = *(const ushort4*)&Gs[(size_t)s4 * 32 + co];
        ushort4 v5 = *(const ushort4*)&Gs[(size_t)s5 * 32 + co];
        ushort4 v6 = *(const ushort4*)&Gs[(size_t)s6 * 32 + co];
        ushort4 v7 = *(const ushort4*)&Gs[(size_t)s7 * 32 + co];
        ax += bf2f(v0.x); ay += bf2f(v0.y); az += bf2f(v0.z); aw += bf2f(v0.w);
        ax += bf2f(v1.x); ay += bf2f(v1.y); az += bf2f(v1.z); aw += bf2f(v1.w);
        ax += bf2f(v2.x); ay += bf2f(v2.y); az += bf2f(v2.z); aw += bf2f(v2.w);
        ax += bf2f(v3.x); ay += bf2f(v3.y); az += bf2f(v3.z); aw += bf2f(v3.w);
        ax += bf2f(v4.x); ay += bf2f(v4.y); az += bf2f(v4.z); aw += bf2f(v4.w);
        ax += bf2f(v5.x); ay += bf2f(v5.y); az += bf2f(v5.z); aw += bf2f(v5.w);
        ax += bf2f(v6.x); ay += bf2f(v6.y); az += bf2f(v6.z); aw += bf2f(v6.w);
        ax += bf2f(v7.x); ay += bf2f(v7.y); az += bf2f(v7.z); aw += bf2f(v7.w);
    }
    for (; e < end; ++e) {
        int s = csr[e];
        ushort4 v = *(const ushort4*)&Gs[(size_t)s * 32 + co];
        ax += bf2f(v.x); ay += bf2f(v.y); az += bf2f(v.z); aw += bf2f(v.w);
    }
    float dv = dinv[d];
    float4 bb = *(const float4*)&b1[c0];
    float zx = fmaxf(dv * ax + bb.x, 0.f);
    float zy = fmaxf(dv * ay + bb.y, 0.f);
    float zz = fmaxf(dv * az + bb.z, 0.f);
    float zw = fmaxf(dv * aw + bb.w, 0.f);
    float2 w0 = *(const float2*)&W2[(c0 + 0) * 2];
    float2 w1 = *(const float2*)&W2[(c0 + 1) * 2];
    float2 w2_ = *(const float2*)&W2[(c0 + 2) * 2];
    float2 w3 = *(const float2*)&W2[(c0 + 3) * 2];
    float p0 = zx * w0.x + zy * w1.x + zz * w2_.x + zw * w3.x;
    float p1 = zx * w0.y + zy * w1.y + zz * w2_.y + zw * w3.y;
    #pragma unroll
    for (int off = 1; off < 8; off <<= 1) {
        p0 += __shfl_xor(p0, off, 64);
        p1 += __shfl_xor(p1, off, 64);
    }
    if (sl == 0)
        *(float2*)&part[((size_t)slab * N_NODES + d) * 2] = make_float2(p0, p1);
}

// ---------------- g2 = dinv * sum_slab(part) ----------------
__global__ __launch_bounds__(256) void g2reduce_kernel(const float* __restrict__ part,
                                                       const float* __restrict__ dinv,
                                                       float* __restrict__ G2) {
    int i = blockIdx.x * 256 + threadIdx.x;
    if (i >= N_NODES) return;
    float a0 = 0.f, a1 = 0.f;
    #pragma unroll
    for (int s = 0; s < 8; ++s) {
        float2 p = *(const float2*)&part[((size_t)s * N_NODES + i) * 2];
        a0 += p.x; a1 += p.y;
    }
    float dv = dinv[i];
    G2[i * 2 + 0] = dv * a0;
    G2[i * 2 + 1] = dv * a1;
}

// ---------------- agg2: 8 nodes/wave, 8 lanes/node ----------------
__global__ __launch_bounds__(256) void agg2_kernel(const float* __restrict__ G2,
                                                   const int* __restrict__ csr,
                                                   const int* __restrict__ rowoff,
                                                   const int* __restrict__ cnt,
                                                   const float* __restrict__ dinv,
                                                   const float* __restrict__ b2,
                                                   float* __restrict__ out) {
    const int tid  = threadIdx.x;
    const int wave = tid >> 6, lane = tid & 63;
    const int g    = lane >> 3, sl = lane & 7;
    const int d    = blockIdx.x * 32 + wave * 8 + g;
    if (d >= N_NODES) return;
    int beg = rowoff[d], num = cnt[d];
    float a0 = 0.f, a1 = 0.f;
    for (int e = sl; e < num; e += 8) {
        int s = csr[beg + e];
        float2 v = *(const float2*)&G2[s * 2];
        a0 += v.x; a1 += v.y;
    }
    #pragma unroll
    for (int off = 1; off < 8; off <<= 1) {
        a0 += __shfl_xor(a0, off, 64);
        a1 += __shfl_xor(a1, off, 64);
    }
    if (sl == 0) {
        float2 self = *(const float2*)&G2[d * 2];
        float dv = dinv[d];
        out[d * 2 + 0] = dv * (a0 + self.x) + b2[0];
        out[d * 2 + 1] = dv * (a1 + self.y) + b2[1];
    }
}

// ---------------- workspace layout (bytes) ----------------
#define OFF_CNT     0u
#define OFF_ROWOFF  262144u
#define OFF_CURSOR  524288u
#define OFF_DINV    786432u
#define OFF_BSUM    1048576u
#define OFF_CSR     1310720u
#define OFF_WP      8388608u     // 512 KB packed single-plane
#define OFF_G1B     9437184u     // 25.6 MB slab-major
#define OFF_G2      35651584u    // 400 KB
#define OFF_PART    36700160u    // 3.2 MB
// total ~40 MB

extern "C" void kernel_launch(void* const* d_in, const int* in_sizes, int n_in,
                              void* d_out, int out_size, void* d_ws, size_t ws_size,
                              hipStream_t stream) {
    const float* x  = (const float*)d_in[0];
    const float* W1 = (const float*)d_in[1];
    const float* b1 = (const float*)d_in[2];
    const float* W2 = (const float*)d_in[3];
    const float* b2 = (const float*)d_in[4];
    const int*   ei = (const int*)d_in[5];

    char* ws = (char*)d_ws;
    int*   cnt    = (int*)  (ws + OFF_CNT);
    int*   rowoff = (int*)  (ws + OFF_ROWOFF);
    int*   cursor = (int*)  (ws + OFF_CURSOR);
    float* dinv   = (float*)(ws + OFF_DINV);
    int*   bsum   = (int*)  (ws + OFF_BSUM);
    int*   csr    = (int*)  (ws + OFF_CSR);
    unsigned short* wp  = (unsigned short*)(ws + OFF_WP);
    unsigned short* g1b = (unsigned short*)(ws + OFF_G1B);
    float* g2     = (float*)(ws + OFF_G2);
    float* part   = (float*)(ws + OFF_PART);
    float* out    = (float*)d_out;

    hipMemsetAsync(cnt, 0, N_NODES * sizeof(int), stream);
    wsplit_kernel<<<1024, 256, 0, stream>>>(W1, wp);
    hist_kernel<<<2048, 256, 0, stream>>>(ei, cnt);
    scan_sums<<<NBLK, 256, 0, stream>>>(cnt, bsum);
    scan_top<<<1, 256, 0, stream>>>(bsum);
    scan_write<<<NBLK, 256, 0, stream>>>(cnt, bsum, rowoff, cursor, dinv);

    gemm_scatter_fused<<<GEMM_BLOCKS + SCAT_BLOCKS, 256, 0, stream>>>(x, wp, dinv, g1b,
                                                                      ei, cursor, csr);

    aggslab_kernel<<<8 * ((N_NODES + 31) / 32), 256, 0, stream>>>(g1b, csr, rowoff, cnt, dinv, b1, W2, part);
    g2reduce_kernel<<<NBLK, 256, 0, stream>>>(part, dinv, g2);
    agg2_kernel<<<(N_NODES + 31) / 32, 256, 0, stream>>>(g2, csr, rowoff, cnt, dinv, b2, out);
}